// Round 10
// baseline (141.929 us; speedup 1.0000x reference)
//
#include <hip/hip_runtime.h>

// MergeLayer: out = sigmoid(relu([z[e0]; z[e1]] @ W1 + b1) @ W2 + b2)
// Factored: g = z @ Wcat (+b1 on gi half)  -- node-level GEMM via bf16 MFMA
//           out[k] = sigmoid(dot(relu(gi[e0]+gj[e1]), W2) + b2)  -- edge gather
//
// Round-10: node_mfma is latency/phase-bound (~32us vs 9us BW floor; 1.7TB/s
// effective): 782 one-shot blocks each pay full z-stage latency with no
// overlap. Change: PERSISTENT node kernel, 391 blocks (all co-resident,
// 2 blocks/CU, exactly 2 tiles each) with double-buffered LDS: next tile's
// z float4 loads issued into registers BEFORE current tile's MFMA+epilogue
// (T14 issue-early/write-late), converted into the spare buffer after.
// A-fragments + bias hoisted (amortized across tiles). Numerics
// bit-identical; wt_build + edge_mlp verbatim R9.
//
// ws layout: gi (N*128 bf16) | gj (N*128 bf16) | Wt (256x128 bf16, 64KB)

#define DD 128

typedef __attribute__((ext_vector_type(8))) short short8;
typedef __attribute__((ext_vector_type(4))) float floatx4;

static __device__ __forceinline__ unsigned short f2bf(float f) {
  unsigned int u = __builtin_bit_cast(unsigned int, f);
  u += 0x7fffu + ((u >> 16) & 1u);   // round-to-nearest-even
  return (unsigned short)(u >> 16);
}
static __device__ __forceinline__ float bflo(unsigned int u) {
  return __builtin_bit_cast(float, u << 16);
}
static __device__ __forceinline__ float bfhi(unsigned int u) {
  return __builtin_bit_cast(float, u & 0xffff0000u);
}

// ---------- prelude: Wt[c][k] = Wcat[k][c] as bf16 ---------------------------
__global__ __launch_bounds__(256) void wt_build(
    const float* __restrict__ W1, unsigned short* __restrict__ Wt) {
  const int g = blockIdx.x * 256 + threadIdx.x;  // 8192 threads total
  const int c = g >> 5;                          // 0..255
  const int kq = (g & 31) * 4;                   // 0..124
  const float* src = (c < 128) ? (W1 + c) : (W1 + 128 * 128 + (c - 128));
  ushort4 o;
  o.x = f2bf(src[(size_t)(kq + 0) * 128]);
  o.y = f2bf(src[(size_t)(kq + 1) * 128]);
  o.z = f2bf(src[(size_t)(kq + 2) * 128]);
  o.w = f2bf(src[(size_t)(kq + 3) * 128]);
  *(ushort4*)&Wt[c * 128 + kq] = o;
}

// ---------- node GEMM: persistent, 8 waves, double-buffered LDS --------------
// Wave w owns channel tiles t = 2w, 2w+1 (32 channels) for ALL 4 node-tiles.
__global__ __launch_bounds__(512, 4) void node_mfma(
    const float* __restrict__ z, const unsigned short* __restrict__ Wt,
    const float* __restrict__ b1, unsigned short* __restrict__ gi,
    unsigned short* __restrict__ gj, int n_nodes) {
  __shared__ __align__(16) unsigned short zb[2][64 * 136];  // 2 x 17.4 KB
  const int tid = threadIdx.x;
  const int w = tid >> 6, lane = tid & 63;
  const int l15 = lane & 15, quad = lane >> 4;
  const int ntiles = (n_nodes + 63) >> 6;

  // hoisted A fragments (W): t_global = w*2+tt; 8 x 16B L1-hot loads
  short8 a[2][4];
#pragma unroll
  for (int tt = 0; tt < 2; ++tt) {
    const unsigned short* wrow =
        Wt + (size_t)((w * 2 + tt) * 16 + l15) * 128 + quad * 8;
#pragma unroll
    for (int s = 0; s < 4; ++s) a[tt][s] = *(const short8*)(wrow + s * 32);
  }
  // hoisted bias (gi half only)
  floatx4 biasv[2];
#pragma unroll
  for (int tt = 0; tt < 2; ++tt) {
    floatx4 b = {0.f, 0.f, 0.f, 0.f};
    if (w < 4) {
      float4 b4 = *(const float4*)&b1[(w * 2 + tt) * 16 + quad * 4];
      b[0] = b4.x; b[1] = b4.y; b[2] = b4.z; b[3] = b4.w;
    }
    biasv[tt] = b;
  }

  int tile = blockIdx.x;
  if (tile >= ntiles) return;   // uniform across block

  // prologue: stage tile 0 into zb[0]
#pragma unroll
  for (int i = 0; i < 4; ++i) {
    int q = tid + i * 512;            // 2048 float4 = 64 nodes x 32
    int nl = q >> 5;
    int node = tile * 64 + nl; if (node >= n_nodes) node = n_nodes - 1;
    float4 v = ((const float4*)z)[(size_t)node * 32 + (q & 31)];
    ushort4 o;
    o.x = f2bf(v.x); o.y = f2bf(v.y); o.z = f2bf(v.z); o.w = f2bf(v.w);
    *(ushort4*)&zb[0][nl * 136 + (q & 31) * 4] = o;
  }
  __syncthreads();

  int cur = 0;
  for (; tile < ntiles; tile += gridDim.x) {
    const int nxt_tile = tile + gridDim.x;
    const bool has_nxt = nxt_tile < ntiles;

    // issue next tile's global loads EARLY (latency hides under MFMA+epilogue)
    float4 v0, v1, v2, v3;
    if (has_nxt) {
      {
        int q = tid;          int nl = q >> 5;
        int node = nxt_tile * 64 + nl; if (node >= n_nodes) node = n_nodes - 1;
        v0 = ((const float4*)z)[(size_t)node * 32 + (q & 31)];
      }
      {
        int q = tid + 512;    int nl = q >> 5;
        int node = nxt_tile * 64 + nl; if (node >= n_nodes) node = n_nodes - 1;
        v1 = ((const float4*)z)[(size_t)node * 32 + (q & 31)];
      }
      {
        int q = tid + 1024;   int nl = q >> 5;
        int node = nxt_tile * 64 + nl; if (node >= n_nodes) node = n_nodes - 1;
        v2 = ((const float4*)z)[(size_t)node * 32 + (q & 31)];
      }
      {
        int q = tid + 1536;   int nl = q >> 5;
        int node = nxt_tile * 64 + nl; if (node >= n_nodes) node = n_nodes - 1;
        v3 = ((const float4*)z)[(size_t)node * 32 + (q & 31)];
      }
    }

    // MFMA over current tile
    floatx4 acc[2][4];  // [tt][nt]
#pragma unroll
    for (int tt = 0; tt < 2; ++tt)
#pragma unroll
      for (int nt = 0; nt < 4; ++nt) acc[tt][nt] = biasv[tt];

#pragma unroll
    for (int nt = 0; nt < 4; ++nt) {
      short8 bz[4];  // B[k=quad*8+j][n=lane&15], n -> node
#pragma unroll
      for (int s = 0; s < 4; ++s)
        bz[s] = *(const short8*)&zb[cur][(nt * 16 + l15) * 136 + s * 32 + quad * 8];
#pragma unroll
      for (int tt = 0; tt < 2; ++tt)
#pragma unroll
        for (int s = 0; s < 4; ++s)
          acc[tt][nt] = __builtin_amdgcn_mfma_f32_16x16x32_bf16(
              a[tt][s], bz[s], acc[tt][nt], 0, 0, 0);
    }

    __syncthreads();   // all zb[cur] reads done; buffer reusable for epilogue

    // epilogue: stage g-tile into zb[cur] per half -> coalesced 16B stores
    const int nb = tile * 64;
#pragma unroll
    for (int half = 0; half < 2; ++half) {
      if ((w >> 2) == half) {   // waves 0-3: gi, waves 4-7: gj
        const int cbase = (w & 3) * 32;
#pragma unroll
        for (int nt = 0; nt < 4; ++nt) {
          const int row = (nt * 16 + l15) * 136;
#pragma unroll
          for (int tt = 0; tt < 2; ++tt) {
            const int c = cbase + tt * 16 + quad * 4;
            ushort4 o;
            o.x = f2bf(acc[tt][nt][0]); o.y = f2bf(acc[tt][nt][1]);
            o.z = f2bf(acc[tt][nt][2]); o.w = f2bf(acc[tt][nt][3]);
            *(ushort4*)&zb[cur][row + c] = o;
          }
        }
      }
      __syncthreads();
      unsigned short* dst = half ? gj : gi;
#pragma unroll
      for (int it = 0; it < 2; ++it) {
        const int u = tid * 8 + it * 4096;
        const int n = u >> 7, c = u & 127;
        const int node = nb + n;
        ushort4 s0 = *(const ushort4*)&zb[cur][n * 136 + c];
        ushort4 s1 = *(const ushort4*)&zb[cur][n * 136 + c + 4];
        if (node < n_nodes) {
          ushort4* gp = (ushort4*)&dst[(size_t)node * 128 + c];
          gp[0] = s0;
          gp[1] = s1;
        }
      }
      __syncthreads();
    }

    // write next tile into the spare buffer (loads have long since returned)
    if (has_nxt) {
      const int nxt = cur ^ 1;
      {
        int q = tid;        int nl = q >> 5;
        ushort4 o; o.x = f2bf(v0.x); o.y = f2bf(v0.y); o.z = f2bf(v0.z); o.w = f2bf(v0.w);
        *(ushort4*)&zb[nxt][nl * 136 + (q & 31) * 4] = o;
      }
      {
        int q = tid + 512;  int nl = q >> 5;
        ushort4 o; o.x = f2bf(v1.x); o.y = f2bf(v1.y); o.z = f2bf(v1.z); o.w = f2bf(v1.w);
        *(ushort4*)&zb[nxt][nl * 136 + (q & 31) * 4] = o;
      }
      {
        int q = tid + 1024; int nl = q >> 5;
        ushort4 o; o.x = f2bf(v2.x); o.y = f2bf(v2.y); o.z = f2bf(v2.z); o.w = f2bf(v2.w);
        *(ushort4*)&zb[nxt][nl * 136 + (q & 31) * 4] = o;
      }
      {
        int q = tid + 1536; int nl = q >> 5;
        ushort4 o; o.x = f2bf(v3.x); o.y = f2bf(v3.y); o.z = f2bf(v3.z); o.w = f2bf(v3.w);
        *(ushort4*)&zb[nxt][nl * 136 + (q & 31) * 4] = o;
      }
    }
    __syncthreads();   // zb[nxt] visible to all before next iteration's MFMA
    cur ^= 1;
  }
}

// ---------- edge phase: persistent, 8 lanes per edge, W2 in registers --------
static __device__ __forceinline__ float dot8(uint4 a, uint4 b, float4 w0, float4 w1) {
  float s;
  s = fmaxf(bflo(a.x) + bflo(b.x), 0.f) * w0.x;
  s = fmaf(fmaxf(bfhi(a.x) + bfhi(b.x), 0.f), w0.y, s);
  s = fmaf(fmaxf(bflo(a.y) + bflo(b.y), 0.f), w0.z, s);
  s = fmaf(fmaxf(bfhi(a.y) + bfhi(b.y), 0.f), w0.w, s);
  s = fmaf(fmaxf(bflo(a.z) + bflo(b.z), 0.f), w1.x, s);
  s = fmaf(fmaxf(bfhi(a.z) + bfhi(b.z), 0.f), w1.y, s);
  s = fmaf(fmaxf(bflo(a.w) + bflo(b.w), 0.f), w1.z, s);
  s = fmaf(fmaxf(bfhi(a.w) + bfhi(b.w), 0.f), w1.w, s);
  return s;
}

__global__ __launch_bounds__(256) void edge_mlp(
    const int* __restrict__ e, const unsigned short* __restrict__ gi,
    const unsigned short* __restrict__ gj, const float* __restrict__ W2,
    const float* __restrict__ b2, float* __restrict__ out, int E) {
  const int p = threadIdx.x & 7;
  // W2 chunk for this lane, held in 16 VGPRs (512B table, L2-hot; once/wave)
  const float4* wv = (const float4*)W2;
  const float4 w0 = wv[p * 2],      w1 = wv[p * 2 + 1];
  const float4 w2 = wv[16 + p * 2], w3 = wv[16 + p * 2 + 1];
  const float bias2 = b2[0];

  const int stride = gridDim.x * 32;  // 32 edges per block per iteration
  for (int edge = blockIdx.x * 32 + (threadIdx.x >> 3); edge < E; edge += stride) {
    const int i = e[edge];
    const int j = e[E + edge];
    // 8 lanes x 16B cover each 128B line of the two 256B rows, fully used.
    const uint4* pi = (const uint4*)(gi + (size_t)i * 128);
    const uint4* pj = (const uint4*)(gj + (size_t)j * 128);
    uint4 a0 = pi[p], a1 = pi[8 + p];
    uint4 c0 = pj[p], c1 = pj[8 + p];
    float acc = dot8(a0, c0, w0, w1) + dot8(a1, c1, w2, w3);
    acc += __shfl_xor(acc, 1);
    acc += __shfl_xor(acc, 2);
    acc += __shfl_xor(acc, 4);
    if (p == 0) {
      float x = acc + bias2;
      out[edge] = 1.f / (1.f + __expf(-x));
    }
  }
}

// ---------- fallback (workspace too small): wave per edge ---------------------
__global__ __launch_bounds__(256) void edge_direct(
    const int* __restrict__ e, const float* __restrict__ z,
    const float* __restrict__ W1, const float* __restrict__ b1,
    const float* __restrict__ W2, const float* __restrict__ b2,
    float* __restrict__ out, int E) {
  const int lane = threadIdx.x & 63;
  const int edge = (int)((blockIdx.x * 256u + threadIdx.x) >> 6);
  if (edge >= E) return;
  const int i = e[edge], j = e[E + edge];
  const float* zi = z + (size_t)i * 128;
  const float* zj = z + (size_t)j * 128;
  const int c0 = lane * 2;
  float h0 = b1[c0], h1 = b1[c0 + 1];
  for (int k = 0; k < 128; ++k) {
    float a = zi[k], b = zj[k];
    float2 wt = *(const float2*)&W1[(size_t)k * 128 + c0];
    float2 wb = *(const float2*)&W1[(size_t)(128 + k) * 128 + c0];
    h0 = fmaf(a, wt.x, h0); h1 = fmaf(a, wt.y, h1);
    h0 = fmaf(b, wb.x, h0); h1 = fmaf(b, wb.y, h1);
  }
  float s = fmaxf(h0, 0.f) * W2[c0] + fmaxf(h1, 0.f) * W2[c0 + 1];
#pragma unroll
  for (int off = 1; off < 64; off <<= 1) s += __shfl_xor(s, off);
  if (lane == 0) out[edge] = 1.f / (1.f + __expf(-(s + b2[0])));
}

extern "C" void kernel_launch(void* const* d_in, const int* in_sizes, int n_in,
                              void* d_out, int out_size, void* d_ws, size_t ws_size,
                              hipStream_t stream) {
  const float* z  = (const float*)d_in[0];
  const int*   e  = (const int*)d_in[1];
  const float* W1 = (const float*)d_in[2];
  const float* b1 = (const float*)d_in[3];
  const float* W2 = (const float*)d_in[4];
  const float* b2 = (const float*)d_in[5];
  float* out = (float*)d_out;
  const int n_nodes = in_sizes[0] / DD;  // 50000
  const int E = in_sizes[1] / 2;         // 600000

  const size_t g_bytes = (size_t)n_nodes * DD * sizeof(unsigned short);
  const size_t wt_bytes = 256 * 128 * sizeof(unsigned short);  // 64 KB

  if (ws_size >= 2 * g_bytes + wt_bytes && n_nodes > 0) {
    unsigned short* gi = (unsigned short*)d_ws;
    unsigned short* gj = (unsigned short*)((char*)d_ws + g_bytes);
    unsigned short* Wt = (unsigned short*)((char*)d_ws + 2 * g_bytes);
    const int ntiles = (n_nodes + 63) / 64;
    int ngrid = (ntiles + 1) / 2;            // all co-resident (2 blocks/CU)
    if (ngrid > 512) ngrid = 512;
    wt_build<<<32, 256, 0, stream>>>(W1, Wt);
    node_mfma<<<ngrid, 512, 0, stream>>>(z, Wt, b1, gi, gj, n_nodes);
    edge_mlp<<<2048, 256, 0, stream>>>(e, gi, gj, W2, b2, out, E);
  } else {
    edge_direct<<<(E + 3) / 4, 256, 0, stream>>>(e, z, W1, b1, W2, b2, out, E);
  }
}

// Round 11
// 114.742 us; speedup vs baseline: 1.2369x; 1.2369x over previous
//
#include <hip/hip_runtime.h>

// MergeLayer: out = sigmoid(relu([z[e0]; z[e1]] @ W1 + b1) @ W2 + b2)
// Factored: g = z @ Wcat (+b1 on gi half)  -- node GEMM via bf16 MFMA
//           out[k] = sigmoid(dot(relu(si*qi[e0]+sj*qj[e1]), W2) + b2)
//
// Round-11: R10's persistent node REGRESSED (+12us) -> reverted to R9's node
// (best: 129.8us). New lever: the edge gather is line-request bound
// (4 x 128B lines/edge, 2.4M lines, 130MB L2-miss measured). Store g as INT8
// with per-row scale: row = 128B -> 2 lines/edge (halved), 16B/lane/row.
// Quant error budget: s~rowmax/127, post-sigmoid error ~0.006 max; combined
// with bf16's 0.0039 stays well under the 0.0187 threshold.
// Node kernel = R9 verbatim except epilogue: 8-thread/node absmax reduce +
// int8 quantize + coalesced 128B stores (+1 fp32 scale per row).
//
// ws layout: gqi (N*128 s8) | gqj (N*128 s8) | sci (N f32) | scj | Wt (64KB)

#define DD 128

typedef __attribute__((ext_vector_type(8))) short short8;
typedef __attribute__((ext_vector_type(4))) float floatx4;

static __device__ __forceinline__ unsigned short f2bf(float f) {
  unsigned int u = __builtin_bit_cast(unsigned int, f);
  u += 0x7fffu + ((u >> 16) & 1u);   // round-to-nearest-even
  return (unsigned short)(u >> 16);
}
static __device__ __forceinline__ float bf2f(unsigned short u) {
  return __builtin_bit_cast(float, (unsigned int)u << 16);
}

// ---------- prelude: Wt[c][k] = Wcat[k][c] as bf16 ---------------------------
__global__ __launch_bounds__(256) void wt_build(
    const float* __restrict__ W1, unsigned short* __restrict__ Wt) {
  const int g = blockIdx.x * 256 + threadIdx.x;  // 8192 threads total
  const int c = g >> 5;                          // 0..255
  const int kq = (g & 31) * 4;                   // 0..124
  const float* src = (c < 128) ? (W1 + c) : (W1 + 128 * 128 + (c - 128));
  ushort4 o;
  o.x = f2bf(src[(size_t)(kq + 0) * 128]);
  o.y = f2bf(src[(size_t)(kq + 1) * 128]);
  o.z = f2bf(src[(size_t)(kq + 2) * 128]);
  o.w = f2bf(src[(size_t)(kq + 3) * 128]);
  *(ushort4*)&Wt[c * 128 + kq] = o;
}

// ---------- node GEMM: 8 waves, 2 channel-tiles/wave, int8 epilogue ----------
// Wave w owns channel tiles t = 2w, 2w+1 (32 channels) for ALL 4 node-tiles.
__global__ __launch_bounds__(512, 4) void node_mfma(
    const float* __restrict__ z, const unsigned short* __restrict__ Wt,
    const float* __restrict__ b1, signed char* __restrict__ gqi,
    signed char* __restrict__ gqj, float* __restrict__ sci,
    float* __restrict__ scj, int n_nodes) {
  __shared__ __align__(16) unsigned short zb[64 * 136];  // 17.4 KB
  const int tid = threadIdx.x;
  const int nb = blockIdx.x * 64;

  // stage z tile -> bf16 LDS (coalesced float4 reads; 4 per thread)
#pragma unroll
  for (int i = 0; i < 4; ++i) {
    int q = tid + i * 512;            // 2048 float4 = 64 nodes x 32
    int nl = q >> 5;
    int node = nb + nl; if (node >= n_nodes) node = n_nodes - 1;
    float4 v = ((const float4*)z)[(size_t)node * 32 + (q & 31)];
    ushort4 o;
    o.x = f2bf(v.x); o.y = f2bf(v.y); o.z = f2bf(v.z); o.w = f2bf(v.w);
    *(ushort4*)&zb[nl * 136 + (q & 31) * 4] = o;
  }

  const int w = tid >> 6, lane = tid & 63;
  const int l15 = lane & 15, quad = lane >> 4;

  // A fragments (W): t_global = w*2+tt; 8 x 16B L1-hot loads
  short8 a[2][4];
#pragma unroll
  for (int tt = 0; tt < 2; ++tt) {
    const unsigned short* wrow =
        Wt + (size_t)((w * 2 + tt) * 16 + l15) * 128 + quad * 8;
#pragma unroll
    for (int s = 0; s < 4; ++s) a[tt][s] = *(const short8*)(wrow + s * 32);
  }

  floatx4 acc[2][4];  // [tt][nt]
#pragma unroll
  for (int tt = 0; tt < 2; ++tt) {
    floatx4 bias = {0.f, 0.f, 0.f, 0.f};
    if (w < 4) {  // gi half: b1 folded; channel = (w*2+tt)*16 + quad*4 + r
      float4 b4 = *(const float4*)&b1[(w * 2 + tt) * 16 + quad * 4];
      bias[0] = b4.x; bias[1] = b4.y; bias[2] = b4.z; bias[3] = b4.w;
    }
#pragma unroll
    for (int nt = 0; nt < 4; ++nt) acc[tt][nt] = bias;
  }

  __syncthreads();

#pragma unroll
  for (int nt = 0; nt < 4; ++nt) {
    short8 bz[4];  // B[k=quad*8+j][n=lane&15], n -> node
#pragma unroll
    for (int s = 0; s < 4; ++s)
      bz[s] = *(const short8*)&zb[(nt * 16 + l15) * 136 + s * 32 + quad * 8];
#pragma unroll
    for (int tt = 0; tt < 2; ++tt)
#pragma unroll
      for (int s = 0; s < 4; ++s)
        acc[tt][nt] = __builtin_amdgcn_mfma_f32_16x16x32_bf16(
            a[tt][s], bz[s], acc[tt][nt], 0, 0, 0);
  }

  // ---- epilogue: stage bf16 in LDS, then absmax + int8 quantize + store ----
  // Stage (per half): col=l15 -> node (nt*16+l15), channel (w&3)*32+tt*16+
  // quad*4+r. Quant: 8 threads/node, 16 ch each, shfl_xor(1,2,4) row max.
  __syncthreads();   // all zb reads done; buffer reusable
#pragma unroll
  for (int half = 0; half < 2; ++half) {
    if ((w >> 2) == half) {   // waves 0-3 stage gi-half, 4-7 stage gj-half
      const int cbase = (w & 3) * 32;
#pragma unroll
      for (int nt = 0; nt < 4; ++nt) {
        const int row = (nt * 16 + l15) * 136;
#pragma unroll
        for (int tt = 0; tt < 2; ++tt) {
          const int c = cbase + tt * 16 + quad * 4;
          ushort4 o;
          o.x = f2bf(acc[tt][nt][0]); o.y = f2bf(acc[tt][nt][1]);
          o.z = f2bf(acc[tt][nt][2]); o.w = f2bf(acc[tt][nt][3]);
          *(ushort4*)&zb[row + c] = o;
        }
      }
    }
    __syncthreads();
    // quantize: thread t -> node tid>>3, channels (tid&7)*16 .. +16
    {
      const int nl = tid >> 3, p8 = tid & 7;
      const int node = nb + nl;
      const unsigned short* rowp = &zb[nl * 136 + p8 * 16];
      ushort4 u0 = *(const ushort4*)(rowp);
      ushort4 u1 = *(const ushort4*)(rowp + 4);
      ushort4 u2 = *(const ushort4*)(rowp + 8);
      ushort4 u3 = *(const ushort4*)(rowp + 12);
      float f[16];
      f[0] = bf2f(u0.x); f[1] = bf2f(u0.y); f[2] = bf2f(u0.z); f[3] = bf2f(u0.w);
      f[4] = bf2f(u1.x); f[5] = bf2f(u1.y); f[6] = bf2f(u1.z); f[7] = bf2f(u1.w);
      f[8] = bf2f(u2.x); f[9] = bf2f(u2.y); f[10] = bf2f(u2.z); f[11] = bf2f(u2.w);
      f[12] = bf2f(u3.x); f[13] = bf2f(u3.y); f[14] = bf2f(u3.z); f[15] = bf2f(u3.w);
      float am = 0.f;
#pragma unroll
      for (int k = 0; k < 16; ++k) am = fmaxf(am, fabsf(f[k]));
      am = fmaxf(am, __shfl_xor(am, 1));
      am = fmaxf(am, __shfl_xor(am, 2));
      am = fmaxf(am, __shfl_xor(am, 4));
      const float inv = (am > 0.f) ? 127.f / am : 0.f;
      unsigned int wd[4];
#pragma unroll
      for (int k2 = 0; k2 < 4; ++k2) {
        unsigned int v = 0;
#pragma unroll
        for (int b = 0; b < 4; ++b) {
          const int q = (int)rintf(f[k2 * 4 + b] * inv);
          v |= ((unsigned int)(q & 0xff)) << (8 * b);
        }
        wd[k2] = v;
      }
      if (node < n_nodes) {
        signed char* dq = half ? gqj : gqi;
        uint4 pk; pk.x = wd[0]; pk.y = wd[1]; pk.z = wd[2]; pk.w = wd[3];
        ((uint4*)(dq + (size_t)node * 128))[p8] = pk;
        if (p8 == 0) (half ? scj : sci)[node] = am * (1.f / 127.f);
      }
    }
    __syncthreads();
  }
}

// ---------- edge phase: persistent, 8 lanes/edge, int8 decode ----------------
// Lane p covers channels p*16..p*16+15: one 16B load per row (2 lines/edge).
__global__ __launch_bounds__(256) void edge_mlp_q(
    const int* __restrict__ e, const signed char* __restrict__ gqi,
    const signed char* __restrict__ gqj, const float* __restrict__ sci,
    const float* __restrict__ scj, const float* __restrict__ W2,
    const float* __restrict__ b2, float* __restrict__ out, int E) {
  const int p = threadIdx.x & 7;
  const float4* wv = (const float4*)W2;
  float4 W[4];   // W2[p*16 .. p*16+16)
#pragma unroll
  for (int k = 0; k < 4; ++k) W[k] = wv[p * 4 + k];
  const float bias2 = b2[0];

  const int stride = gridDim.x * 32;  // 32 edges per block per iteration
  for (int edge = blockIdx.x * 32 + (threadIdx.x >> 3); edge < E; edge += stride) {
    const int i = e[edge];
    const int j = e[E + edge];
    const float si = sci[i];            // broadcast (8 lanes same addr)
    const float sj = scj[j];
    const uint4 qa = ((const uint4*)(gqi + (size_t)i * 128))[p];
    const uint4 qb = ((const uint4*)(gqj + (size_t)j * 128))[p];
    const unsigned int ua[4] = {qa.x, qa.y, qa.z, qa.w};
    const unsigned int ub[4] = {qb.x, qb.y, qb.z, qb.w};
    float acc = 0.f;
#pragma unroll
    for (int k = 0; k < 4; ++k) {
      const float wk[4] = {W[k].x, W[k].y, W[k].z, W[k].w};
#pragma unroll
      for (int b = 0; b < 4; ++b) {
        const float af = (float)(int)(signed char)(ua[k] >> (8 * b));
        const float bf = (float)(int)(signed char)(ub[k] >> (8 * b));
        const float h = fmaf(si, af, sj * bf);
        acc = fmaf(fmaxf(h, 0.f), wk[b], acc);
      }
    }
    acc += __shfl_xor(acc, 1);
    acc += __shfl_xor(acc, 2);
    acc += __shfl_xor(acc, 4);
    if (p == 0) {
      out[edge] = 1.f / (1.f + __expf(-(acc + bias2)));
    }
  }
}

// ---------- fallback (workspace too small): wave per edge ---------------------
__global__ __launch_bounds__(256) void edge_direct(
    const int* __restrict__ e, const float* __restrict__ z,
    const float* __restrict__ W1, const float* __restrict__ b1,
    const float* __restrict__ W2, const float* __restrict__ b2,
    float* __restrict__ out, int E) {
  const int lane = threadIdx.x & 63;
  const int edge = (int)((blockIdx.x * 256u + threadIdx.x) >> 6);
  if (edge >= E) return;
  const int i = e[edge], j = e[E + edge];
  const float* zi = z + (size_t)i * 128;
  const float* zj = z + (size_t)j * 128;
  const int c0 = lane * 2;
  float h0 = b1[c0], h1 = b1[c0 + 1];
  for (int k = 0; k < 128; ++k) {
    float a = zi[k], b = zj[k];
    float2 wt = *(const float2*)&W1[(size_t)k * 128 + c0];
    float2 wb = *(const float2*)&W1[(size_t)(128 + k) * 128 + c0];
    h0 = fmaf(a, wt.x, h0); h1 = fmaf(a, wt.y, h1);
    h0 = fmaf(b, wb.x, h0); h1 = fmaf(b, wb.y, h1);
  }
  float s = fmaxf(h0, 0.f) * W2[c0] + fmaxf(h1, 0.f) * W2[c0 + 1];
#pragma unroll
  for (int off = 1; off < 64; off <<= 1) s += __shfl_xor(s, off);
  if (lane == 0) out[edge] = 1.f / (1.f + __expf(-(s + b2[0])));
}

extern "C" void kernel_launch(void* const* d_in, const int* in_sizes, int n_in,
                              void* d_out, int out_size, void* d_ws, size_t ws_size,
                              hipStream_t stream) {
  const float* z  = (const float*)d_in[0];
  const int*   e  = (const int*)d_in[1];
  const float* W1 = (const float*)d_in[2];
  const float* b1 = (const float*)d_in[3];
  const float* W2 = (const float*)d_in[4];
  const float* b2 = (const float*)d_in[5];
  float* out = (float*)d_out;
  const int n_nodes = in_sizes[0] / DD;  // 50000
  const int E = in_sizes[1] / 2;         // 600000

  const size_t gq_bytes = (size_t)n_nodes * DD;            // int8 rows
  const size_t sc_bytes = (size_t)n_nodes * sizeof(float);
  const size_t wt_bytes = 256 * 128 * sizeof(unsigned short);  // 64 KB
  const size_t need = 2 * gq_bytes + 2 * sc_bytes + wt_bytes;

  if (ws_size >= need && n_nodes > 0) {
    signed char* gqi = (signed char*)d_ws;
    signed char* gqj = gqi + gq_bytes;
    float* sci = (float*)((char*)d_ws + 2 * gq_bytes);
    float* scj = (float*)((char*)d_ws + 2 * gq_bytes + sc_bytes);
    unsigned short* Wt =
        (unsigned short*)((char*)d_ws + 2 * gq_bytes + 2 * sc_bytes);
    wt_build<<<32, 256, 0, stream>>>(W1, Wt);
    node_mfma<<<(n_nodes + 63) / 64, 512, 0, stream>>>(z, Wt, b1, gqi, gqj,
                                                       sci, scj, n_nodes);
    edge_mlp_q<<<2048, 256, 0, stream>>>(e, gqi, gqj, sci, scj, W2, b2, out, E);
  } else {
    edge_direct<<<(E + 3) / 4, 256, 0, stream>>>(e, z, W1, b1, W2, b2, out, E);
  }
}

// Round 12
// 113.906 us; speedup vs baseline: 1.2460x; 1.0073x over previous
//
#include <hip/hip_runtime.h>

// MergeLayer: out = sigmoid(relu([z[e0]; z[e1]] @ W1 + b1) @ W2 + b2)
// Factored: g = z @ Wcat (+b1 on gi half)  -- node GEMM via bf16 MFMA
//           out[k] = sigmoid(dot(relu(si*qi[e0]+sj*qj[e1]), W2) + b2)
//
// Round-12: node epilogue rebuilt. R11's epilogue did fp32->bf16->LDS->
// fp32->int8 twice (once per half; 4 barriers, half the waves idle each
// pass). Now: row-absmax via shfl_xor(16/32) quad-reduce + one LDS
// atomicMax per (node,half); each wave quantizes DIRECTLY from its fp32
// accumulators into a padded [64][33]-word int8 LDS tile (33 = 1 mod 32:
// bank-friendly); both halves concurrent (waves 0-3 gi, 4-7 gj); single
// barrier; 512 threads copy out coalesced 32B chunks + scales.
// Barriers 6 -> 3, no bf16 round-trip. Edge kernel = R11 verbatim.
//
// ws layout: gqi (N*128 s8) | gqj (N*128 s8) | sci (N f32) | scj | Wt (64KB)

#define DD 128

typedef __attribute__((ext_vector_type(8))) short short8;
typedef __attribute__((ext_vector_type(4))) float floatx4;

static __device__ __forceinline__ unsigned short f2bf(float f) {
  unsigned int u = __builtin_bit_cast(unsigned int, f);
  u += 0x7fffu + ((u >> 16) & 1u);   // round-to-nearest-even
  return (unsigned short)(u >> 16);
}

// ---------- prelude: Wt[c][k] = Wcat[k][c] as bf16 ---------------------------
__global__ __launch_bounds__(256) void wt_build(
    const float* __restrict__ W1, unsigned short* __restrict__ Wt) {
  const int g = blockIdx.x * 256 + threadIdx.x;  // 8192 threads total
  const int c = g >> 5;                          // 0..255
  const int kq = (g & 31) * 4;                   // 0..124
  const float* src = (c < 128) ? (W1 + c) : (W1 + 128 * 128 + (c - 128));
  ushort4 o;
  o.x = f2bf(src[(size_t)(kq + 0) * 128]);
  o.y = f2bf(src[(size_t)(kq + 1) * 128]);
  o.z = f2bf(src[(size_t)(kq + 2) * 128]);
  o.w = f2bf(src[(size_t)(kq + 3) * 128]);
  *(ushort4*)&Wt[c * 128 + kq] = o;
}

// ---------- node GEMM: 8 waves, 2 channel-tiles/wave, direct-int8 epilogue ---
// Wave w owns channel tiles t = 2w, 2w+1 (32 channels) for ALL 4 node-tiles.
__global__ __launch_bounds__(512, 4) void node_mfma(
    const float* __restrict__ z, const unsigned short* __restrict__ Wt,
    const float* __restrict__ b1, signed char* __restrict__ gqi,
    signed char* __restrict__ gqj, float* __restrict__ sci,
    float* __restrict__ scj, int n_nodes) {
  __shared__ __align__(16) unsigned short zb[64 * 136];   // 17.4 KB
  __shared__ unsigned int ep[2 * 64 * 33];                // 16.9 KB int8 tiles
  __shared__ unsigned int smax[2][64];                    // row absmax bits
  const int tid = threadIdx.x;
  const int nb = blockIdx.x * 64;

  if (tid < 128) smax[tid >> 6][tid & 63] = 0u;

  // stage z tile -> bf16 LDS (coalesced float4 reads; 4 per thread)
#pragma unroll
  for (int i = 0; i < 4; ++i) {
    int q = tid + i * 512;            // 2048 float4 = 64 nodes x 32
    int nl = q >> 5;
    int node = nb + nl; if (node >= n_nodes) node = n_nodes - 1;
    float4 v = ((const float4*)z)[(size_t)node * 32 + (q & 31)];
    ushort4 o;
    o.x = f2bf(v.x); o.y = f2bf(v.y); o.z = f2bf(v.z); o.w = f2bf(v.w);
    *(ushort4*)&zb[nl * 136 + (q & 31) * 4] = o;
  }

  const int w = tid >> 6, lane = tid & 63;
  const int l15 = lane & 15, quad = lane >> 4;

  // A fragments (W): t_global = w*2+tt; 8 x 16B L1-hot loads
  short8 a[2][4];
#pragma unroll
  for (int tt = 0; tt < 2; ++tt) {
    const unsigned short* wrow =
        Wt + (size_t)((w * 2 + tt) * 16 + l15) * 128 + quad * 8;
#pragma unroll
    for (int s = 0; s < 4; ++s) a[tt][s] = *(const short8*)(wrow + s * 32);
  }

  floatx4 acc[2][4];  // [tt][nt]
#pragma unroll
  for (int tt = 0; tt < 2; ++tt) {
    floatx4 bias = {0.f, 0.f, 0.f, 0.f};
    if (w < 4) {  // gi half: b1 folded; channel = (w*2+tt)*16 + quad*4 + r
      float4 b4 = *(const float4*)&b1[(w * 2 + tt) * 16 + quad * 4];
      bias[0] = b4.x; bias[1] = b4.y; bias[2] = b4.z; bias[3] = b4.w;
    }
#pragma unroll
    for (int nt = 0; nt < 4; ++nt) acc[tt][nt] = bias;
  }

  __syncthreads();   // zb staged + smax zeroed

#pragma unroll
  for (int nt = 0; nt < 4; ++nt) {
    short8 bz[4];  // B[k=quad*8+j][n=lane&15], n -> node
#pragma unroll
    for (int s = 0; s < 4; ++s)
      bz[s] = *(const short8*)&zb[(nt * 16 + l15) * 136 + s * 32 + quad * 8];
#pragma unroll
    for (int tt = 0; tt < 2; ++tt)
#pragma unroll
      for (int s = 0; s < 4; ++s)
        acc[tt][nt] = __builtin_amdgcn_mfma_f32_16x16x32_bf16(
            a[tt][s], bz[s], acc[tt][nt], 0, 0, 0);
  }

  // ---- epilogue: direct fp32 -> int8, both halves concurrent ----
  // C layout: col=l15 -> node (nt*16+l15); row=quad*4+r -> channel
  // (w&3)*32 + tt*16 + quad*4 + r.  half = w>>2 (0: gi, 1: gj).
  const int half = w >> 2;
  const int cbase = (w & 3) * 32;

  // 1) per-node absmax: wave-local over 8 values, quad-combine via shfl,
  //    cross-wave via LDS atomicMax (values >= 0 so uint order == float).
#pragma unroll
  for (int nt = 0; nt < 4; ++nt) {
    float m = 0.f;
#pragma unroll
    for (int tt = 0; tt < 2; ++tt)
#pragma unroll
      for (int r = 0; r < 4; ++r) m = fmaxf(m, fabsf(acc[tt][nt][r]));
    m = fmaxf(m, __shfl_xor(m, 16));
    m = fmaxf(m, __shfl_xor(m, 32));
    if (lane < 16)
      atomicMax(&smax[half][nt * 16 + lane], __float_as_uint(m));
  }
  __syncthreads();

  // 2) quantize own values, pack 4x int8 -> u32, write padded LDS tile
#pragma unroll
  for (int nt = 0; nt < 4; ++nt) {
    const int node_l = nt * 16 + l15;
    const float am = __uint_as_float(smax[half][node_l]);
    const float inv = (am > 0.f) ? 127.f / am : 0.f;
#pragma unroll
    for (int tt = 0; tt < 2; ++tt) {
      unsigned int v = 0;
#pragma unroll
      for (int r = 0; r < 4; ++r) {
        const int q = (int)rintf(acc[tt][nt][r] * inv);
        v |= ((unsigned int)(q & 0xff)) << (8 * r);
      }
      ep[half * 2112 + node_l * 33 + ((cbase + tt * 16 + quad * 4) >> 2)] = v;
    }
  }
  __syncthreads();

  // 3) copy out: 512 threads cover 2 halves x 64 nodes x 128B in one round
  {
    const int hh = tid >> 8;         // 0..1
    const int sub = tid & 255;
    const int nl = sub >> 2;
    const int c32 = (sub & 3) * 32;  // byte offset within row
    const int node = nb + nl;
    const unsigned int* rp = &ep[hh * 2112 + nl * 33 + (c32 >> 2)];
    uint4 o0, o1;
    o0.x = rp[0]; o0.y = rp[1]; o0.z = rp[2]; o0.w = rp[3];
    o1.x = rp[4]; o1.y = rp[5]; o1.z = rp[6]; o1.w = rp[7];
    if (node < n_nodes) {
      signed char* dq = hh ? gqj : gqi;
      uint4* gp = (uint4*)(dq + (size_t)node * 128 + c32);
      gp[0] = o0; gp[1] = o1;
    }
    if (tid < 128) {
      const int h2 = tid >> 6, n2 = tid & 63;
      const int node2 = nb + n2;
      if (node2 < n_nodes) {
        const float amv = __uint_as_float(smax[h2][n2]);
        (h2 ? scj : sci)[node2] = amv * (1.f / 127.f);
      }
    }
  }
}

// ---------- edge phase: persistent, 8 lanes/edge, int8 decode ----------------
// Lane p covers channels p*16..p*16+15: one 16B load per row (2 lines/edge).
__global__ __launch_bounds__(256) void edge_mlp_q(
    const int* __restrict__ e, const signed char* __restrict__ gqi,
    const signed char* __restrict__ gqj, const float* __restrict__ sci,
    const float* __restrict__ scj, const float* __restrict__ W2,
    const float* __restrict__ b2, float* __restrict__ out, int E) {
  const int p = threadIdx.x & 7;
  const float4* wv = (const float4*)W2;
  float4 W[4];   // W2[p*16 .. p*16+16)
#pragma unroll
  for (int k = 0; k < 4; ++k) W[k] = wv[p * 4 + k];
  const float bias2 = b2[0];

  const int stride = gridDim.x * 32;  // 32 edges per block per iteration
  for (int edge = blockIdx.x * 32 + (threadIdx.x >> 3); edge < E; edge += stride) {
    const int i = e[edge];
    const int j = e[E + edge];
    const float si = sci[i];            // broadcast (8 lanes same addr)
    const float sj = scj[j];
    const uint4 qa = ((const uint4*)(gqi + (size_t)i * 128))[p];
    const uint4 qb = ((const uint4*)(gqj + (size_t)j * 128))[p];
    const unsigned int ua[4] = {qa.x, qa.y, qa.z, qa.w};
    const unsigned int ub[4] = {qb.x, qb.y, qb.z, qb.w};
    float acc = 0.f;
#pragma unroll
    for (int k = 0; k < 4; ++k) {
      const float wk[4] = {W[k].x, W[k].y, W[k].z, W[k].w};
#pragma unroll
      for (int b = 0; b < 4; ++b) {
        const float af = (float)(int)(signed char)(ua[k] >> (8 * b));
        const float bf = (float)(int)(signed char)(ub[k] >> (8 * b));
        const float h = fmaf(si, af, sj * bf);
        acc = fmaf(fmaxf(h, 0.f), wk[b], acc);
      }
    }
    acc += __shfl_xor(acc, 1);
    acc += __shfl_xor(acc, 2);
    acc += __shfl_xor(acc, 4);
    if (p == 0) {
      out[edge] = 1.f / (1.f + __expf(-(acc + bias2)));
    }
  }
}

// ---------- fallback (workspace too small): wave per edge ---------------------
__global__ __launch_bounds__(256) void edge_direct(
    const int* __restrict__ e, const float* __restrict__ z,
    const float* __restrict__ W1, const float* __restrict__ b1,
    const float* __restrict__ W2, const float* __restrict__ b2,
    float* __restrict__ out, int E) {
  const int lane = threadIdx.x & 63;
  const int edge = (int)((blockIdx.x * 256u + threadIdx.x) >> 6);
  if (edge >= E) return;
  const int i = e[edge], j = e[E + edge];
  const float* zi = z + (size_t)i * 128;
  const float* zj = z + (size_t)j * 128;
  const int c0 = lane * 2;
  float h0 = b1[c0], h1 = b1[c0 + 1];
  for (int k = 0; k < 128; ++k) {
    float a = zi[k], b = zj[k];
    float2 wt = *(const float2*)&W1[(size_t)k * 128 + c0];
    float2 wb = *(const float2*)&W1[(size_t)(128 + k) * 128 + c0];
    h0 = fmaf(a, wt.x, h0); h1 = fmaf(a, wt.y, h1);
    h0 = fmaf(b, wb.x, h0); h1 = fmaf(b, wb.y, h1);
  }
  float s = fmaxf(h0, 0.f) * W2[c0] + fmaxf(h1, 0.f) * W2[c0 + 1];
#pragma unroll
  for (int off = 1; off < 64; off <<= 1) s += __shfl_xor(s, off);
  if (lane == 0) out[edge] = 1.f / (1.f + __expf(-(s + b2[0])));
}

extern "C" void kernel_launch(void* const* d_in, const int* in_sizes, int n_in,
                              void* d_out, int out_size, void* d_ws, size_t ws_size,
                              hipStream_t stream) {
  const float* z  = (const float*)d_in[0];
  const int*   e  = (const int*)d_in[1];
  const float* W1 = (const float*)d_in[2];
  const float* b1 = (const float*)d_in[3];
  const float* W2 = (const float*)d_in[4];
  const float* b2 = (const float*)d_in[5];
  float* out = (float*)d_out;
  const int n_nodes = in_sizes[0] / DD;  // 50000
  const int E = in_sizes[1] / 2;         // 600000

  const size_t gq_bytes = (size_t)n_nodes * DD;            // int8 rows
  const size_t sc_bytes = (size_t)n_nodes * sizeof(float);
  const size_t wt_bytes = 256 * 128 * sizeof(unsigned short);  // 64 KB
  const size_t need = 2 * gq_bytes + 2 * sc_bytes + wt_bytes;

  if (ws_size >= need && n_nodes > 0) {
    signed char* gqi = (signed char*)d_ws;
    signed char* gqj = gqi + gq_bytes;
    float* sci = (float*)((char*)d_ws + 2 * gq_bytes);
    float* scj = (float*)((char*)d_ws + 2 * gq_bytes + sc_bytes);
    unsigned short* Wt =
        (unsigned short*)((char*)d_ws + 2 * gq_bytes + 2 * sc_bytes);
    wt_build<<<32, 256, 0, stream>>>(W1, Wt);
    node_mfma<<<(n_nodes + 63) / 64, 512, 0, stream>>>(z, Wt, b1, gqi, gqj,
                                                       sci, scj, n_nodes);
    edge_mlp_q<<<2048, 256, 0, stream>>>(e, gqi, gqj, sci, scj, W2, b2, out, E);
  } else {
    edge_direct<<<(E + 3) / 4, 256, 0, stream>>>(e, z, W1, b1, W2, b2, out, E);
  }
}